// Round 6
// baseline (1091.006 us; speedup 1.0000x reference)
//
#include <hip/hip_runtime.h>

typedef unsigned short u16;
typedef unsigned int   u32;
typedef __attribute__((ext_vector_type(8))) short short8;
typedef __attribute__((ext_vector_type(4))) float f4;

#define BT 16
#define TX 30
#define TY 10

__device__ __forceinline__ float bf2f_u16(u16 h){ u32 i=((u32)h)<<16; float f; __builtin_memcpy(&f,&i,4); return f; }
__device__ __forceinline__ float lo2f(u32 p){ u32 i=p<<16; float f; __builtin_memcpy(&f,&i,4); return f; }
__device__ __forceinline__ float hi2f(u32 p){ u32 i=p&0xffff0000u; float f; __builtin_memcpy(&f,&i,4); return f; }
__device__ __forceinline__ u16 f2bf(float f){ u32 x; __builtin_memcpy(&x,&f,4); u32 r=(x+0x7fffu+((x>>16)&1u))>>16; return (u16)r; }

#if __has_builtin(__builtin_amdgcn_rcpf)
__device__ __forceinline__ float frcp(float x){ return __builtin_amdgcn_rcpf(x); }
#else
__device__ __forceinline__ float frcp(float x){ return 1.0f/x; }
#endif
__device__ __forceinline__ float sigm(float x){ return frcp(1.0f+__expf(-x)); }
__device__ __forceinline__ float tanh_(float x){ x=fminf(fmaxf(x,-15.0f),15.0f); float e=__expf(2.0f*x); return 1.0f - 2.0f*frcp(e+1.0f); }

__device__ __forceinline__ f4 mfma16(short8 a, short8 b, f4 c){
    return __builtin_amdgcn_mfma_f32_16x16x32_bf16(a, b, c, 0, 0, 0);
}

union S8u { short8 s; u32 u[4]; };

// pack hi-halves of two fp32 into one u32 (truncated bf16 pair), residual -> lo pair
__device__ __forceinline__ void cvt_pair(float a0, float a1, u32& hp, u32& lp){
    u32 u0, u1; __builtin_memcpy(&u0,&a0,4); __builtin_memcpy(&u1,&a1,4);
    hp = __builtin_amdgcn_perm(u1, u0, 0x07060302u);
    float r0 = a0 - hi2f(u0);
    float r1 = a1 - hi2f(u1);
    u32 v0, v1; __builtin_memcpy(&v0,&r0,4); __builtin_memcpy(&v1,&r1,4);
    lp = __builtin_amdgcn_perm(v1, v0, 0x07060302u);
}

// LDS [*][64]-u16 tiles (sh/sl/ctx; and `a` in the fallback variant) use an
// involutive 16B-block XOR swizzle: phys_blk = blk ^ (key&7), same on wr/rd.
struct SEnc  { u16 h[2][2][2][BT][40]; };                // 10240 B
struct SDecL { u16 sh[BT][64], sl[BT][64], ctxh[BT][64], ctxl[BT][64]; float en[BT*TX]; };                      // 10112 B
struct SDecG { u16 sh[BT][64], sl[BT][64], ctxh[BT][64], ctxl[BT][64]; float en[BT*TX]; float aW1[BT*TX*10]; }; // 29312 B
template<bool AG> struct SmemT;
template<> struct SmemT<false> { u16 a[BT*TX][64]; union { SEnc e; SDecL d; } u; }; // 71680 -> 2 blk/CU
template<> struct SmemT<true>  { union { SEnc e; SDecG d; } u; };                   // 29312 -> LDS allows 5; VGPR(128) caps 4 blk/CU
static_assert(sizeof(SmemT<false>) == 71680, "fallback LDS");
static_assert(sizeof(SmemT<true>)  == 29312, "global-a LDS");

// AG=true: `a` lives in d_ws (per-block 480x64 u16), LDS small -> 4 blocks/CU.
//          aW1 (ty-invariant) cached in LDS: phase A = 4 MFMAs not 8.
// AG=false: exact round-5 kernel (proven 366us) as runtime fallback.
template<bool AG>
__global__ __launch_bounds__(256, AG ? 4 : 2) void fused_kernel(
    const float* __restrict__ X,
    const float* __restrict__ Wihf, const float* __restrict__ Whhf, const float* __restrict__ bfv,
    const float* __restrict__ Wihr, const float* __restrict__ Whhr, const float* __restrict__ brv,
    const float* __restrict__ W1, const float* __restrict__ b1, const float* __restrict__ W2, const float* __restrict__ b2,
    const float* __restrict__ Wihp, const float* __restrict__ Whhp, const float* __restrict__ bp,
    const float* __restrict__ Wo, const float* __restrict__ bo,
    u16* __restrict__ aws,
    float* __restrict__ out)
{
    __shared__ __align__(16) SmemT<AG> sm;
    const int tid = threadIdx.x;
    const int b0  = blockIdx.x * BT;

    u16* awb = nullptr;
    if constexpr (AG) awb = aws + (size_t)blockIdx.x * (BT*TX*64);

    const int lane = tid & 63;
    const int wv   = tid >> 6;     // wave 0..3
    const int mL   = lane & 15;    // frag non-K index
    const int qL   = lane >> 4;    // quad
    const int k0q  = qL * 8;
    const int ed   = wv >> 1;      // encoder dir
    const int ub   = (wv & 1) * 16;// encoder unit base within NA=32

    {   // zero encoder h buffers (10240 B)
        u32* p = (u32*)&sm.u.e;
        for (int i = tid; i < 2560; i += 256) p[i] = 0u;
    }
    __syncthreads();

    // ===================== encoder =====================
    const float* Wih = ed ? Wihr : Wihf;
    const float* Whh = ed ? Whhr : Whhf;
    const float* bv  = ed ? brv  : bfv;

    short8 Bih[4][4]; short8 Bhh[4]; float bias4[4];
    #pragma unroll
    for (int gt = 0; gt < 4; gt++){
        const int n = gt*32 + ub + mL;                  // gate row (i,f,g,o chunks of 32)
        #pragma unroll
        for (int kt = 0; kt < 4; kt++){
            const float* p = Wih + n*128 + kt*32 + k0q;
            short8 s;
            #pragma unroll
            for (int j = 0; j < 8; j++) s[j] = (short)f2bf(p[j]);
            Bih[gt][kt] = s;
        }
        {
            const float* p = Whh + n*32 + k0q;
            short8 s;
            #pragma unroll
            for (int j = 0; j < 8; j++) s[j] = (short)f2bf(p[j]);
            Bhh[gt] = s;
        }
        bias4[gt] = bv[n];
    }

    const float* xrow = X + ((long)(b0 + mL)) * TX * 128;   // A row = batch mL
    float cst[4] = {0.f,0.f,0.f,0.f};                        // c-state, fully lane-resident

    // single step t: all 16 batches in one fragment (full lanes in cell update)
    auto estep = [&](int t, f4* cur, f4* nxt){
        if (t + 1 < TX){                                 // prefetch next step
            const int ts = ed ? (TX-2-t) : (t+1);
            const float* p = xrow + ts*128 + k0q;
            #pragma unroll
            for (int kt = 0; kt < 4; kt++){
                nxt[2*kt]   = *(const f4*)(p + kt*32);
                nxt[2*kt+1] = *(const f4*)(p + kt*32 + 4);
            }
        }
        const int rb = (t+1) & 1, wb = t & 1;

        f4 acc[4];
        #pragma unroll
        for (int gt = 0; gt < 4; gt++) acc[gt] = (f4){bias4[gt],bias4[gt],bias4[gt],bias4[gt]};

        #pragma unroll
        for (int kt = 0; kt < 4; kt++){                  // x-GEMM
            S8u xh, xl;
            cvt_pair(cur[2*kt][0],   cur[2*kt][1],   xh.u[0], xl.u[0]);
            cvt_pair(cur[2*kt][2],   cur[2*kt][3],   xh.u[1], xl.u[1]);
            cvt_pair(cur[2*kt+1][0], cur[2*kt+1][1], xh.u[2], xl.u[2]);
            cvt_pair(cur[2*kt+1][2], cur[2*kt+1][3], xh.u[3], xl.u[3]);
            #pragma unroll
            for (int gt = 0; gt < 4; gt++){
                acc[gt] = mfma16(xh.s, Bih[gt][kt], acc[gt]);
                acc[gt] = mfma16(xl.s, Bih[gt][kt], acc[gt]);
            }
        }
        {   // h-MFMA: A = h_{t-1}, all 16 rows real
            const short8 Ahh = *(const short8*)&sm.u.e.h[rb][ed][0][mL][k0q];
            const short8 Ahl = *(const short8*)&sm.u.e.h[rb][ed][1][mL][k0q];
            #pragma unroll
            for (int gt = 0; gt < 4; gt++){
                acc[gt] = mfma16(Ahh, Bhh[gt], acc[gt]);
                acc[gt] = mfma16(Ahl, Bhh[gt], acc[gt]);
            }
        }
        const int tpos = ed ? (TX-1-t) : t;
        const int u = ed*32 + ub + mL;
        #pragma unroll
        for (int reg = 0; reg < 4; reg++){               // cell update: ALL 64 lanes
            const int m = qL*4 + reg;
            const float ii = sigm(acc[0][reg]), ff = sigm(acc[1][reg]);
            const float gg = tanh_(acc[2][reg]), oo = sigm(acc[3][reg]);
            cst[reg] = ff*cst[reg] + ii*gg;
            const float hh = oo * tanh_(cst[reg]);
            const u16 hhi = f2bf(hh);
            const u16 hlo = f2bf(hh - bf2f_u16(hhi));
            sm.u.e.h[wb][ed][0][m][ub+mL] = hhi;
            sm.u.e.h[wb][ed][1][m][ub+mL] = hlo;
            const int r = m*TX + tpos;
            if constexpr (AG) awb[r*64 + u] = hhi;       // plain layout in global
            else sm.a[r][(((u>>3) ^ ((m+tpos)&7))<<3) | (u&7)] = hhi;
        }
        __syncthreads();
    };

    f4 rawA[8], rawB[8];
    {   // initial load: step 0
        const int ts0 = ed ? (TX-1) : 0;
        const float* p = xrow + ts0*128 + k0q;
        #pragma unroll
        for (int kt = 0; kt < 4; kt++){
            rawA[2*kt]   = *(const f4*)(p + kt*32);
            rawA[2*kt+1] = *(const f4*)(p + kt*32 + 4);
        }
    }
    for (int t = 0; t < TX; t += 2){ estep(t, rawA, rawB); estep(t+1, rawB, rawA); }

    // ===================== decoder setup =====================
    {   // zero sh, sl (contiguous 4096 B)
        u32* z = (u32*)sm.u.d.sh;
        for (int i = tid; i < 1024; i += 256) z[i] = 0u;
    }
    const u16* aflat;
    if constexpr (AG) aflat = awb; else aflat = &sm.a[0][0];

    // e = tanh(a @ W1[:,:64].T + s @ W1[:,64:].T + b1); en = relu(e . w2 + b2)
    short8 W1aB[2][2];                                   // W1[:, :64] hi/lo B-frags
    #pragma unroll
    for (int kt = 0; kt < 2; kt++){
        short8 hv8, lv8;
        #pragma unroll
        for (int j = 0; j < 8; j++){
            const float v = (mL < 10) ? W1[mL*128 + kt*32 + k0q + j] : 0.f;
            const u16 hb = f2bf(v);
            hv8[j] = (short)hb;
            lv8[j] = (short)f2bf(v - bf2f_u16(hb));
        }
        W1aB[kt][0] = hv8; W1aB[kt][1] = lv8;
    }
    short8 W1sB[2];                                      // W1[:, 64:128] hi B-frag
    #pragma unroll
    for (int kt = 0; kt < 2; kt++){
        short8 s;
        #pragma unroll
        for (int j = 0; j < 8; j++){
            const float v = (mL < 10) ? W1[mL*128 + 64 + kt*32 + k0q + j] : 0.f;
            s[j] = (short)f2bf(v);
        }
        W1sB[kt] = s;
    }
    const float b1v = (mL < 10) ? b1[mL] : 0.f;
    const float w2v = (mL < 10) ? W2[mL] : 0.f;
    const float b2s = b2[0];

    if constexpr (AG){
        // aW1 = b1 + a @ W1[:,:64].T  (ty-invariant) -> LDS, once.
        // Writes SDecG.aW1 (overlaps dead SEnc.h region; encoder done).
        for (int tile = wv; tile < 30; tile += 4){
            f4 accA = (f4){b1v, b1v, b1v, b1v};
            const u16* ab = aflat + (tile*16 + mL)*64;
            #pragma unroll
            for (int kt = 0; kt < 2; kt++){
                const short8 av = *(const short8*)(ab + kt*32 + k0q);
                accA = mfma16(av, W1aB[kt][0], accA);
                accA = mfma16(av, W1aB[kt][1], accA);
            }
            if (mL < 10){
                #pragma unroll
                for (int reg = 0; reg < 4; reg++)
                    sm.u.d.aW1[(tile*16 + qL*4 + reg)*10 + mL] = accA[reg];
            }
        }
    }

    const int uw = wv * 16;                              // decoder unit base (NS=64 over 4 waves)
    short8 Bip[4][2], Bhp[4][2]; float pb4[4];
    #pragma unroll
    for (int gt = 0; gt < 4; gt++){
        const int n = gt*64 + uw + mL;
        #pragma unroll
        for (int kt = 0; kt < 2; kt++){
            const float* p = Wihp + n*64 + kt*32 + k0q;
            const float* q = Whhp + n*64 + kt*32 + k0q;
            short8 s1v, s2v;
            #pragma unroll
            for (int j = 0; j < 8; j++){ s1v[j] = (short)f2bf(p[j]); s2v[j] = (short)f2bf(q[j]); }
            Bip[gt][kt] = s1v; Bhp[gt][kt] = s2v;
        }
        pb4[gt] = bp[n];
    }
    short8 Bo2[2];
    {
        const int n = uw + mL;
        #pragma unroll
        for (int kt = 0; kt < 2; kt++){
            const float* p = Wo + n*64 + kt*32 + k0q;
            short8 s;
            #pragma unroll
            for (int j = 0; j < 8; j++) s[j] = (short)f2bf(p[j]);
            Bo2[kt] = s;
        }
    }
    const float boL = bo[uw + mL];
    float cs2[4] = {0.f,0.f,0.f,0.f};
    u16* shf = &sm.u.d.sh[0][0];
    u16* slf = &sm.u.d.sl[0][0];
    u16* chf = &sm.u.d.ctxh[0][0];
    u16* clf = &sm.u.d.ctxl[0][0];
    __syncthreads();

    // ===================== decoder loop (4 barriers/ty) =====================
    for (int ty = 0; ty < TY; ty++){
        // phase A: en for all 480 (b,t) rows
        for (int tt = wv; tt < TX; tt += 4){
            const int r = tt*16 + mL;
            const int b = (r * 34953) >> 20;             // r/30 for r<480
            const int tp2 = r - b*30;
            f4 accE;
            if constexpr (AG){                           // init from cached aW1 (output rows)
                #pragma unroll
                for (int reg = 0; reg < 4; reg++)
                    accE[reg] = (mL < 10) ? sm.u.d.aW1[(tt*16 + qL*4 + reg)*10 + mL] : 0.f;
            } else {
                accE = (f4){b1v, b1v, b1v, b1v};
                const u16* ab = aflat + r*64;
                const int keyA = (b + tp2) & 7;
                #pragma unroll
                for (int kt = 0; kt < 2; kt++){
                    const short8 av = *(const short8*)(ab + (((kt*4+qL)^keyA)<<3));
                    accE = mfma16(av, W1aB[kt][0], accE);
                    accE = mfma16(av, W1aB[kt][1], accE);
                }
            }
            const int keyS = b & 7;
            #pragma unroll
            for (int kt = 0; kt < 2; kt++){
                const int off = b*64 + (((kt*4+qL)^keyS)<<3);
                const short8 shh = *(const short8*)(shf + off);
                const short8 sll = *(const short8*)(slf + off);
                accE = mfma16(shh, W1sB[kt], accE);
                accE = mfma16(sll, W1sB[kt], accE);
            }
            float er[4];
            #pragma unroll
            for (int reg = 0; reg < 4; reg++) er[reg] = w2v * tanh_(accE[reg]);
            #pragma unroll
            for (int d = 1; d < 16; d <<= 1){
                #pragma unroll
                for (int reg = 0; reg < 4; reg++) er[reg] += __shfl_xor(er[reg], d);
            }
            if (mL == 0){
                f4 ev;
                #pragma unroll
                for (int reg = 0; reg < 4; reg++) ev[reg] = fmaxf(er[reg] + b2s, 0.f);
                *(f4*)&sm.u.d.en[tt*16 + qL*4] = ev;
            }
        }
        __syncthreads();
        {   // fused softmax+context: 16 rows x 16 lanes, 4 units/lane
            const int cr = tid >> 4, cup = tid & 15;
            const float* enr = &sm.u.d.en[cr*30];
            float mx = enr[0];
            #pragma unroll
            for (int t2 = 1; t2 < TX; t2++) mx = fmaxf(mx, enr[t2]);
            float ssum = 0.f, s0 = 0.f, s1 = 0.f, s2v_ = 0.f, s3 = 0.f;
            #pragma unroll 5
            for (int t2 = 0; t2 < TX; t2++){
                const float e = __expf(enr[t2]-mx);
                const u16* ap;
                if constexpr (AG) ap = aflat + (cr*30+t2)*64 + (cup<<2);
                else ap = aflat + (cr*30+t2)*64
                              + ((((cup>>1) ^ ((cr+t2)&7))<<3) | ((cup&1)<<2));
                const u32 pa0 = *(const u32*)ap;
                const u32 pa1 = *(const u32*)(ap + 2);
                ssum += e;
                s0 += e*lo2f(pa0); s1 += e*hi2f(pa0);
                s2v_ += e*lo2f(pa1); s3 += e*hi2f(pa1);
            }
            const float inv = frcp(ssum);
            s0 *= inv; s1 *= inv; s2v_ *= inv; s3 *= inv;
            const u16 h0 = f2bf(s0), h1 = f2bf(s1), h2 = f2bf(s2v_), h3 = f2bf(s3);
            const u16 l0 = f2bf(s0 - bf2f_u16(h0)), l1 = f2bf(s1 - bf2f_u16(h1));
            const u16 l2 = f2bf(s2v_ - bf2f_u16(h2)), l3 = f2bf(s3 - bf2f_u16(h3));
            const int off = cr*64 + ((((cup>>1) ^ (cr&7))<<3) | ((cup&1)<<2));
            *(u32*)(chf + off)     = (u32)h0 | ((u32)h1 << 16);
            *(u32*)(chf + off + 2) = (u32)h2 | ((u32)h3 << 16);
            *(u32*)(clf + off)     = (u32)l0 | ((u32)l1 << 16);
            *(u32*)(clf + off + 2) = (u32)l2 | ((u32)l3 << 16);
        }
        __syncthreads();
        // z2 = [ctx|s] @ Wp^T + bp : all 16 A-rows real
        f4 acc2[4];
        #pragma unroll
        for (int gt = 0; gt < 4; gt++) acc2[gt] = (f4){pb4[gt],pb4[gt],pb4[gt],pb4[gt]};
        #pragma unroll
        for (int kt = 0; kt < 2; kt++){
            const int off = mL*64 + (((kt*4+qL) ^ (mL&7))<<3);
            const short8 ch  = *(const short8*)(chf + off);
            const short8 cl  = *(const short8*)(clf + off);
            const short8 shh = *(const short8*)(shf + off);
            const short8 sll = *(const short8*)(slf + off);
            #pragma unroll
            for (int gt = 0; gt < 4; gt++){
                acc2[gt] = mfma16(ch,  Bip[gt][kt], acc2[gt]);
                acc2[gt] = mfma16(cl,  Bip[gt][kt], acc2[gt]);
                acc2[gt] = mfma16(shh, Bhp[gt][kt], acc2[gt]);
                acc2[gt] = mfma16(sll, Bhp[gt][kt], acc2[gt]);
            }
        }
        __syncthreads();                                 // frag reads done before s overwrite
        #pragma unroll
        for (int reg = 0; reg < 4; reg++){               // cell update: ALL 64 lanes
            const int m = qL*4 + reg;
            const float ii = sigm(acc2[0][reg]), ff = sigm(acc2[1][reg]);
            const float gg = tanh_(acc2[2][reg]), oo = sigm(acc2[3][reg]);
            cs2[reg] = ff*cs2[reg] + ii*gg;
            const float sv = oo * tanh_(cs2[reg]);
            const u16 shi = f2bf(sv);
            const u16 slo = f2bf(sv - bf2f_u16(shi));
            const int u2 = uw + mL;
            const int idx = m*64 + ((((u2>>3) ^ (m&7))<<3) | (u2&7));
            shf[idx] = shi;
            slf[idx] = slo;
        }
        __syncthreads();
        // out = s @ Wo^T + bo  (reads sh/sl; next phaseA also only reads -> no barrier)
        f4 acc3 = (f4){boL, boL, boL, boL};
        #pragma unroll
        for (int kt = 0; kt < 2; kt++){
            const int off = mL*64 + (((kt*4+qL) ^ (mL&7))<<3);
            const short8 shh = *(const short8*)(shf + off);
            const short8 sll = *(const short8*)(slf + off);
            acc3 = mfma16(shh, Bo2[kt], acc3);
            acc3 = mfma16(sll, Bo2[kt], acc3);
        }
        #pragma unroll
        for (int reg = 0; reg < 4; reg++){
            const int m = qL*4 + reg;
            out[(((long)(b0+m))*TY + ty)*64 + uw + mL] = acc3[reg];
        }
    }
}

extern "C" void kernel_launch(void* const* d_in, const int* in_sizes, int n_in,
                              void* d_out, int out_size, void* d_ws, size_t ws_size,
                              hipStream_t stream) {
    const float* X    = (const float*)d_in[0];
    const float* Wihf = (const float*)d_in[1];
    const float* Whhf = (const float*)d_in[2];
    const float* bfv  = (const float*)d_in[3];
    const float* Wihr = (const float*)d_in[4];
    const float* Whhr = (const float*)d_in[5];
    const float* brv  = (const float*)d_in[6];
    const float* W1   = (const float*)d_in[7];
    const float* b1   = (const float*)d_in[8];
    const float* W2   = (const float*)d_in[9];
    const float* b2   = (const float*)d_in[10];
    const float* Wihp = (const float*)d_in[11];
    const float* Whhp = (const float*)d_in[12];
    const float* bp   = (const float*)d_in[13];
    const float* Wo   = (const float*)d_in[14];
    const float* bo   = (const float*)d_in[15];
    float* out = (float*)d_out;

    const int B  = in_sizes[0] / (TX * 128);
    const int nb = B / BT;
    dim3 grid(nb), block(256);
    const size_t need = (size_t)nb * (BT*TX*64) * sizeof(u16);  // per-block a slab
    if (d_ws != nullptr && ws_size >= need){
        fused_kernel<true><<<grid, block, 0, stream>>>(
            X, Wihf, Whhf, bfv, Wihr, Whhr, brv,
            W1, b1, W2, b2, Wihp, Whhp, bp, Wo, bo, (u16*)d_ws, out);
    } else {
        fused_kernel<false><<<grid, block, 0, stream>>>(
            X, Wihf, Whhf, bfv, Wihr, Whhr, brv,
            W1, b1, W2, b2, Wihp, Whhp, bp, Wo, bo, nullptr, out);
    }
}